// Round 8
// baseline (388.978 us; speedup 1.0000x reference)
//
#include <hip/hip_runtime.h>

typedef unsigned short u16;
typedef unsigned int u32;
typedef short short8 __attribute__((ext_vector_type(8)));
typedef float f32x4 __attribute__((ext_vector_type(4)));

#define NB   512
#define NPG  211
#define NOBJ 10
#define NVAL 200
#define NE   420
#define NN   (NB * NPG)

__device__ __forceinline__ float bf2f(u16 u){
  union { unsigned i; float f; } v; v.i = ((unsigned)u) << 16; return v.f;
}
__device__ __forceinline__ u16 f2bf(float f){
  union { float f; unsigned i; } v; v.f = f;
  return (u16)((v.i + 0x7FFFu + ((v.i >> 16) & 1u)) >> 16);
}
__device__ __forceinline__ float lo_bf(u32 u){ union{u32 i;float f;}v; v.i=u<<16; return v.f; }
__device__ __forceinline__ float hi_bf(u32 u){ union{u32 i;float f;}v; v.i=u&0xffff0000u; return v.f; }
__device__ __forceinline__ u32 pack_bf(float a, float b){ return (u32)f2bf(a) | ((u32)f2bf(b)<<16); }
__device__ __forceinline__ float lrelu(float s){ return s > 0.f ? s : 0.2f * s; }
__device__ __forceinline__ short8 pack8(ushort4 a, ushort4 b){
  short8 v;
  v[0]=(short)a.x; v[1]=(short)a.y; v[2]=(short)a.z; v[3]=(short)a.w;
  v[4]=(short)b.x; v[5]=(short)b.y; v[6]=(short)b.z; v[7]=(short)b.w;
  return v;
}
// XOR swizzle inside a [*][128] u16 LDS tile, 4-element chunk granularity.
__device__ __forceinline__ int swz(int r, int c){
  return (r << 7) + (((c & ~3) ^ ((r & 15) << 2)) | (c & 3));
}

// ---------------- prep: transposed weights, f32 -> bf16 (ws) ----------------
__global__ __launch_bounds__(256) void k_prept(const float* __restrict__ W1, const float* __restrict__ W2,
                                               u16* __restrict__ W1t, u16* __restrict__ W2t){
  int gid = blockIdx.x * 256 + threadIdx.x;      // 320 blocks -> 81920
  if (gid < 16384){
    int k = gid >> 7, n = gid & 127;
    W1t[n * 128 + k] = f2bf(W1[k * 128 + n]);
  } else {
    int t = gid - 16384;
    int n = t >> 9, kk = t & 511;
    int h = kk >> 7, c = kk & 127;
    W2t[n * 512 + kk] = f2bf(W2[c * 512 + h * 128 + n]);
  }
}

// ---------------- prep: layer-2 attention vectors (ws, f32) ----------------
__global__ __launch_bounds__(256) void k_prepwm(const float* __restrict__ W2, const float* __restrict__ as2,
                                                const float* __restrict__ ad2,
                                                float* __restrict__ wms, float* __restrict__ wmd){
  int gid = blockIdx.x * 256 + threadIdx.x;      // 4 blocks -> 1024
  int which = gid >> 9, hk = gid & 511;
  int h = hk >> 7, k = hk & 127;
  const float* av = which ? ad2 : as2;
  float s = 0.f;
  for (int j = 0; j < 128; ++j)
    s += W2[k * 512 + h * 128 + j] * av[h * 128 + j];
  (which ? wmd : wms)[hk] = s;
}

// =====================================================================
// ===================== SPLIT PIPELINE KERNELS ========================
// =====================================================================

// ---- embed: x[n][c] bf16 (linear layout) ----
__global__ __launch_bounds__(256) void k_embed2(
    const float* __restrict__ head, const float* __restrict__ obj, const float* __restrict__ val,
    const float* __restrict__ Wh, const float* __restrict__ bh,
    const float* __restrict__ Wo, const float* __restrict__ bo,
    const float* __restrict__ Wv, const float* __restrict__ bv,
    u16* __restrict__ x){
  int gid = blockIdx.x * 256 + threadIdx.x;      // 13504 blocks = NN*32
  int n = gid >> 5, cc = (gid & 31) << 2;
  int g = n / NPG, loc = n - g * NPG;
  float a[4];
  if (loc == 0){
    const float* in = head + (size_t)g * 2;
    float i0 = in[0], i1 = in[1];
    #pragma unroll
    for (int t = 0; t < 4; ++t){ int c = cc + t; a[t] = bh[c] + i0 * Wh[c] + i1 * Wh[128 + c]; }
  } else if (loc <= NOBJ){
    const float* in = obj + ((size_t)g * NOBJ + (loc - 1)) * 2;
    float i0 = in[0], i1 = in[1];
    #pragma unroll
    for (int t = 0; t < 4; ++t){ int c = cc + t; a[t] = bo[c] + i0 * Wo[c] + i1 * Wo[128 + c]; }
  } else {
    const float* in = val + ((size_t)g * NVAL + (loc - 11)) * 5;
    float f[5];
    #pragma unroll
    for (int k = 0; k < 5; ++k) f[k] = in[k];
    #pragma unroll
    for (int t = 0; t < 4; ++t){
      int c = cc + t; float s = bv[c];
      #pragma unroll
      for (int k = 0; k < 5; ++k) s += f[k] * Wv[k * 128 + c];
      a[t] = s;
    }
  }
  ushort4 u;
  u.x = f2bf(fmaxf(a[0], 0.f)); u.y = f2bf(fmaxf(a[1], 0.f));
  u.z = f2bf(fmaxf(a[2], 0.f)); u.w = f2bf(fmaxf(a[3], 0.f));
  *(ushort4*)&x[(size_t)n * 128 + cc] = u;
}

// ---- CSR build: per-graph block ----
__global__ __launch_bounds__(256) void k_csr2(const int* __restrict__ eidx,
                                              int* __restrict__ coff, int* __restrict__ csrc){
  __shared__ int sEs[420], sEd[420], sTmp[256], sOff[212], sSrc[632];
  int g = blockIdx.x, tid = threadIdx.x;
  const int4* e4 = (const int4*)(eidx + (size_t)g * 840);
  for (int i = tid; i < 105; i += 256){ ((int4*)sEs)[i] = e4[i]; ((int4*)sEd)[i] = e4[105 + i]; }
  __syncthreads();
  int deg = 0;
  if (tid < NPG){
    deg = 1;
    const int4* p4 = (const int4*)sEd;
    #pragma unroll 4
    for (int i = 0; i < 105; ++i){
      int4 v = p4[i];
      deg += (v.x == tid) + (v.y == tid) + (v.z == tid) + (v.w == tid);
    }
  }
  int v = deg;
  #pragma unroll
  for (int st = 1; st < 256; st <<= 1){
    sTmp[tid] = v;
    __syncthreads();
    if (tid >= st) v += sTmp[tid - st];
    __syncthreads();
  }
  if (tid < NPG) sOff[tid] = v - deg;
  if (tid == NPG - 1) sOff[NPG] = v;
  __syncthreads();
  if (tid < NPG){
    int p = sOff[tid];
    sSrc[p++] = tid;                              // self loop first
    const int4* pd4 = (const int4*)sEd;
    const int4* ps4 = (const int4*)sEs;
    for (int i = 0; i < 105; ++i){
      int4 d = pd4[i]; int4 s = ps4[i];
      if (d.x == tid) sSrc[p++] = s.x;
      if (d.y == tid) sSrc[p++] = s.y;
      if (d.z == tid) sSrc[p++] = s.z;
      if (d.w == tid) sSrc[p++] = s.w;
    }
  }
  __syncthreads();
  if (tid < 212) coff[(size_t)g * 212 + tid] = sOff[tid];
  for (int i = tid; i < 631; i += 256) csrc[(size_t)g * 632 + i] = sSrc[i];
}

// ---- MFMA GEMM: C[M x 128] = sum_ch A_ch[M x 128] @ Bt[128 x (ch*128..)]^T ----
// 844 blocks x 256 thr; wave w owns row-tiles {2w,2w+1}; 8 col-tiles.
template<int KCH, bool RELU>
__global__ __launch_bounds__(256) void k_mm(const u16* __restrict__ A, size_t chunkStride,
                                            const u16* __restrict__ Bt, int bstride,
                                            const float* __restrict__ bias, u16* __restrict__ C){
  __shared__ u16 sA[128 * 128];
  const int tid = threadIdx.x, lane = tid & 63, w = tid >> 6;
  const int l15 = lane & 15, lg = lane >> 4;
  const int row0 = blockIdx.x * 128;
  f32x4 acc[2][8];
  #pragma unroll
  for (int mi = 0; mi < 2; ++mi)
    #pragma unroll
    for (int ni = 0; ni < 8; ++ni) acc[mi][ni] = (f32x4){0,0,0,0};

  #pragma unroll 1
  for (int ch = 0; ch < KCH; ++ch){
    const u16* Ab = A + (size_t)ch * chunkStride + (size_t)row0 * 128;
    #pragma unroll
    for (int q0 = 0; q0 < 2048; q0 += 256){
      int q = q0 + tid;
      int r = q >> 4, c8 = (q & 15) << 3;
      ushort4 v0 = *(const ushort4*)(Ab + r * 128 + c8);
      ushort4 v1 = *(const ushort4*)(Ab + r * 128 + c8 + 4);
      *(ushort4*)&sA[swz(r, c8)]     = v0;
      *(ushort4*)&sA[swz(r, c8 + 4)] = v1;
    }
    __syncthreads();
    #pragma unroll
    for (int kk = 0; kk < 4; ++kk){
      int k0 = kk * 32 + (lg << 2);
      short8 af[2];
      #pragma unroll
      for (int mi = 0; mi < 2; ++mi){
        int rr = (w * 2 + mi) * 16 + l15;
        af[mi] = pack8(*(const ushort4*)&sA[swz(rr, k0)],
                       *(const ushort4*)&sA[swz(rr, k0 + 16)]);
      }
      #pragma unroll
      for (int ni = 0; ni < 8; ++ni){
        const u16* Bp = Bt + (size_t)(ni * 16 + l15) * bstride + ch * 128 + k0;
        short8 bf = pack8(*(const ushort4*)Bp, *(const ushort4*)(Bp + 16));
        acc[0][ni] = __builtin_amdgcn_mfma_f32_16x16x32_bf16(af[0], bf, acc[0][ni], 0, 0, 0);
        acc[1][ni] = __builtin_amdgcn_mfma_f32_16x16x32_bf16(af[1], bf, acc[1][ni], 0, 0, 0);
      }
    }
    __syncthreads();
  }
  #pragma unroll
  for (int mi = 0; mi < 2; ++mi){
    int r0 = row0 + (w * 2 + mi) * 16 + (lg << 2);
    #pragma unroll
    for (int ni = 0; ni < 8; ++ni){
      int col = ni * 16 + l15;
      float bv = RELU ? bias[col] : 0.f;
      #pragma unroll
      for (int r = 0; r < 4; ++r){
        float v = acc[mi][ni][r];
        if (RELU) v = fmaxf(v + bv, 0.f);
        C[(size_t)(r0 + r) * 128 + col] = f2bf(v);
      }
    }
  }
}

// ---- att1 logits: thread per (n,h), 32-col head slice ----
__global__ __launch_bounds__(256) void k_att1k(const u16* __restrict__ xs1,
                                               const float* __restrict__ as1, const float* __restrict__ ad1,
                                               float* __restrict__ Ls, float* __restrict__ Ld){
  int t = blockIdx.x * 256 + threadIdx.x;        // 1688 blocks = NN*4
  int n = t >> 2, h = t & 3;
  const u16* xr = xs1 + (size_t)n * 128 + h * 32;
  float s = 0.f, d = 0.f;
  #pragma unroll
  for (int j = 0; j < 8; ++j){
    ushort4 xv = *(const ushort4*)(xr + j * 4);
    #pragma unroll
    for (int q = 0; q < 4; ++q){
      float xf = bf2f(((const u16*)&xv)[q]);
      int c = h * 32 + j * 4 + q;
      s += xf * as1[c];
      d += xf * ad1[c];
    }
  }
  Ls[t] = s; Ld[t] = d;
}

// ---- att2 logits: thread per (n,h), full 128-col dot with wms/wmd ----
__global__ __launch_bounds__(256) void k_att2k(const u16* __restrict__ x1,
                                               const float* __restrict__ wms, const float* __restrict__ wmd,
                                               float* __restrict__ Ls, float* __restrict__ Ld){
  __shared__ float sw[1024];
  int tid = threadIdx.x;
  for (int i = tid; i < 512; i += 256) sw[i] = wms[i];
  for (int i = tid; i < 512; i += 256) sw[512 + i] = wmd[i];
  __syncthreads();
  int t = blockIdx.x * 256 + tid;                // 1688 blocks
  int n = t >> 2, h = t & 3;
  const u16* xr = x1 + (size_t)n * 128;
  const float* wsp = sw + h * 128;
  const float* wdp = sw + 512 + h * 128;
  float s = 0.f, d = 0.f;
  #pragma unroll
  for (int j = 0; j < 32; ++j){
    ushort4 xv = *(const ushort4*)(xr + j * 4);
    #pragma unroll
    for (int q = 0; q < 4; ++q){
      float xf = bf2f(((const u16*)&xv)[q]);
      s += xf * wsp[j * 4 + q];
      d += xf * wdp[j * 4 + q];
    }
  }
  Ls[t] = s; Ld[t] = d;
}

// ---- softmax weights: thread per (dst,h); writes raw exp + folded recip-denom ----
__global__ __launch_bounds__(256) void k_smk(const float* __restrict__ Ls, const float* __restrict__ Ld,
                                             const int* __restrict__ coff, const int* __restrict__ csrc,
                                             float* __restrict__ wn, float* __restrict__ rden, float fold){
  int g = blockIdx.x >> 2;
  int t = ((blockIdx.x & 3) << 8) + threadIdx.x; // 0..1023
  if (t >= NPG * 4) return;
  int dst = t >> 2, h = t & 3;
  int gb = g * NPG;
  int o0 = coff[(size_t)g * 212 + dst], o1 = coff[(size_t)g * 212 + dst + 1];
  const int* sp = csrc + (size_t)g * 632;
  float ad = Ld[(size_t)(gb + dst) * 4 + h];
  float m = -3e38f;
  for (int e = o0; e < o1; ++e) m = fmaxf(m, lrelu(Ls[(size_t)(gb + sp[e]) * 4 + h] + ad));
  float dn = 0.f;
  float* wp = wn + (size_t)g * 2528 + h * 632;
  for (int e = o0; e < o1; ++e){
    float ee = __expf(lrelu(Ls[(size_t)(gb + sp[e]) * 4 + h] + ad) - m);
    wp[e] = ee; dn += ee;
  }
  rden[(size_t)(gb + dst) * 4 + h] = fold / (dn + 1e-16f);
}

// ---- gat1: wave per dst, thread per col-pair; x1 = relu(b1 + A~xs1) ----
__global__ __launch_bounds__(256) void k_gat1k(const u16* __restrict__ xs1,
                                               const float* __restrict__ wn, const float* __restrict__ rden,
                                               const int* __restrict__ coff, const int* __restrict__ csrc,
                                               const float* __restrict__ b1, u16* __restrict__ x1){
  int bid = blockIdx.x;                          // 512*53
  int g = bid / 53, ch = bid - g * 53;
  int dst = ch * 4 + (threadIdx.x >> 6);
  if (dst >= NPG) return;
  int lane = threadIdx.x & 63;
  int cp = lane << 1, hh = lane >> 4;
  int gb = g * NPG;
  int o0 = coff[(size_t)g * 212 + dst], o1 = coff[(size_t)g * 212 + dst + 1];
  const int* sp = csrc + (size_t)g * 632;
  const float* wp = wn + (size_t)g * 2528 + hh * 632;
  float a0 = 0.f, a1 = 0.f;
  for (int e = o0; e < o1; ++e){
    int src = sp[e];
    u32 f = *(const u32*)&xs1[(size_t)(gb + src) * 128 + cp];
    float w = wp[e];
    a0 += w * lo_bf(f); a1 += w * hi_bf(f);
  }
  float rv = rden[(size_t)(gb + dst) * 4 + hh];
  *(u32*)&x1[(size_t)(gb + dst) * 128 + cp] =
    pack_bf(fmaxf(a0 * rv + b1[cp], 0.f), fmaxf(a1 * rv + b1[cp + 1], 0.f));
}

// ---- gat2: wave per dst, all 4 heads per thread; writes y[h][n][c] (fold=0.25 in rden) ----
__global__ __launch_bounds__(256) void k_gat2k(const u16* __restrict__ x1,
                                               const float* __restrict__ wn, const float* __restrict__ rden,
                                               const int* __restrict__ coff, const int* __restrict__ csrc,
                                               u16* __restrict__ y){
  int bid = blockIdx.x;                          // 512*53
  int g = bid / 53, ch = bid - g * 53;
  int dst = ch * 4 + (threadIdx.x >> 6);
  if (dst >= NPG) return;
  int lane = threadIdx.x & 63;
  int cp = lane << 1;
  int gb = g * NPG;
  int o0 = coff[(size_t)g * 212 + dst], o1 = coff[(size_t)g * 212 + dst + 1];
  const int* sp = csrc + (size_t)g * 632;
  const float* wb = wn + (size_t)g * 2528;
  float a0[4] = {0,0,0,0}, a1[4] = {0,0,0,0};
  for (int e = o0; e < o1; ++e){
    int src = sp[e];
    u32 f = *(const u32*)&x1[(size_t)(gb + src) * 128 + cp];
    float xl = lo_bf(f), xh = hi_bf(f);
    #pragma unroll
    for (int h = 0; h < 4; ++h){
      float w = wb[h * 632 + e];
      a0[h] += w * xl; a1[h] += w * xh;
    }
  }
  #pragma unroll
  for (int h = 0; h < 4; ++h){
    float rv = rden[(size_t)(gb + dst) * 4 + h];
    *(u32*)&y[(size_t)h * NN * 128 + (size_t)(gb + dst) * 128 + cp] =
      pack_bf(a0[h] * rv, a1[h] * rv);
  }
}

// ---- final projections: 4 blocks/graph, 4 threads/output ----
__global__ __launch_bounds__(256) void k_final2(const u16* __restrict__ out2, const float* __restrict__ amask,
                                                const float* __restrict__ Wacc, const float* __restrict__ bacc,
                                                const float* __restrict__ Woff, const float* __restrict__ boff,
                                                const float* __restrict__ Wvf,  const float* __restrict__ bvf,
                                                float* __restrict__ out){
  int g = blockIdx.x >> 2;
  int t = ((blockIdx.x & 3) << 8) + threadIdx.x; // 0..1023
  if (t >= 812) return;
  int o = t >> 2, q = t & 3;
  float s = 0.f;
  if (o < 200){
    const u16* row = out2 + (size_t)(g * NPG + 11 + o) * 128;
    #pragma unroll
    for (int j = 0; j < 8; ++j){
      int c = q * 32 + j * 4;
      ushort4 xv = *(const ushort4*)(row + c);
      s += bf2f(xv.x)*Woff[c] + bf2f(xv.y)*Woff[c+1] + bf2f(xv.z)*Woff[c+2] + bf2f(xv.w)*Woff[c+3];
    }
  } else if (o < 202){
    int j2 = o - 200;
    const u16* row = out2 + (size_t)(g * NPG) * 128;
    #pragma unroll
    for (int j = 0; j < 8; ++j){
      int c = q * 32 + j * 4;
      ushort4 xv = *(const ushort4*)(row + c);
      s += bf2f(xv.x)*Wacc[c*2+j2] + bf2f(xv.y)*Wacc[(c+1)*2+j2]
         + bf2f(xv.z)*Wacc[(c+2)*2+j2] + bf2f(xv.w)*Wacc[(c+3)*2+j2];
    }
  } else {
    const u16* row = out2 + (size_t)(g * NPG) * 128;
    #pragma unroll
    for (int j = 0; j < 8; ++j){
      int c = q * 32 + j * 4;
      ushort4 xv = *(const ushort4*)(row + c);
      s += bf2f(xv.x)*Wvf[c] + bf2f(xv.y)*Wvf[c+1] + bf2f(xv.z)*Wvf[c+2] + bf2f(xv.w)*Wvf[c+3];
    }
  }
  s += __shfl_xor(s, 1);
  s += __shfl_xor(s, 2);
  if (q == 0){
    if (o < 200){
      out[(size_t)g * 203 + 2 + o] = s + boff[0];
    } else if (o < 202){
      int j2 = o - 200;
      float lm = logf(amask[g * 2 + j2]);
      out[(size_t)g * 203 + j2] = s + bacc[j2] + fmaxf(lm, -3.402823466e38f);
    } else {
      out[(size_t)g * 203 + 202] = s + bvf[0];
    }
  }
}

// =====================================================================
// ============== FUSED FALLBACK (R6, validated, verbatim) =============
// =====================================================================
__global__ __launch_bounds__(1024, 1) void k_graph(
    const float* __restrict__ head, const float* __restrict__ obj, const float* __restrict__ val,
    const int* __restrict__ eidx, const float* __restrict__ amask,
    const float* __restrict__ Wh, const float* __restrict__ bh,
    const float* __restrict__ Wo, const float* __restrict__ bo,
    const float* __restrict__ Wv, const float* __restrict__ bv,
    const u16* __restrict__ W1t, const float* __restrict__ as1, const float* __restrict__ ad1,
    const float* __restrict__ b1,
    const u16* __restrict__ W2t, const float* __restrict__ wms, const float* __restrict__ wmd,
    const float* __restrict__ b2,
    const float* __restrict__ Wacc, const float* __restrict__ bacc,
    const float* __restrict__ Woff, const float* __restrict__ boff,
    const float* __restrict__ Wvf,  const float* __restrict__ bvf,
    float* __restrict__ out)
{
  __shared__ __align__(16) char sm[135008];
  u16*   sX   = (u16*)sm;
  u16*   sY   = (u16*)(sm + 54016);
  float* sLs  = (float*)(sm + 108032);
  float* sLd  = (float*)(sm + 111408);
  float* sW   = (float*)(sm + 114784);
  float* sDen = (float*)(sm + 124896);
  int*   sEs  = (int*)(sm + 128272);
  int*   sEd  = (int*)(sm + 129952);
  int*   sOff = (int*)(sm + 131632);
  int*   sSrc = (int*)(sm + 132480);

  const int b    = blockIdx.x;
  const int tid  = threadIdx.x;
  const int lane = tid & 63;
  const int wv   = tid >> 6;
  const int l15  = lane & 15;
  const int lg   = lane >> 4;
  const int cp   = lane << 1;
  const int cHi  = cp & ~3, cLo = cp & 3;
  const int hh   = lane >> 4;

  int tmi[4], tcb[4]; bool tact[4];
  #pragma unroll
  for (int s = 0; s < 4; ++s){
    int t = wv + (s << 4);
    tact[s] = t < 56; tmi[s] = t >> 2; tcb[s] = (t & 3) << 5;
  }

  const int* eg = eidx + (size_t)b * 2 * NE;
  if (tid < NE){ sEs[tid] = eg[tid]; sEd[tid] = eg[NE + tid]; }
  else if (tid >= 512 && tid < 640)      sDen[tid - 512] = as1[tid - 512];
  else if (tid >= 640 && tid < 768)      sDen[tid - 512] = ad1[tid - 640];

  for (int it = tid; it < NPG * 32; it += 1024){
    int n = it >> 5, cc = (it & 31) << 2;
    float a[4];
    if (n == 0){
      const float* in = head + (size_t)b * 2;
      float i0 = in[0], i1 = in[1];
      #pragma unroll
      for (int t = 0; t < 4; ++t){ int c = cc + t; a[t] = bh[c] + i0 * Wh[c] + i1 * Wh[128 + c]; }
    } else if (n <= NOBJ){
      const float* in = obj + ((size_t)b * NOBJ + (n - 1)) * 2;
      float i0 = in[0], i1 = in[1];
      #pragma unroll
      for (int t = 0; t < 4; ++t){ int c = cc + t; a[t] = bo[c] + i0 * Wo[c] + i1 * Wo[128 + c]; }
    } else {
      const float* in = val + ((size_t)b * NVAL + (n - 11)) * 5;
      float f[5];
      #pragma unroll
      for (int k = 0; k < 5; ++k) f[k] = in[k];
      #pragma unroll
      for (int t = 0; t < 4; ++t){
        int c = cc + t; float s = bv[c];
        #pragma unroll
        for (int k = 0; k < 5; ++k) s += f[k] * Wv[k * 128 + c];
        a[t] = s;
      }
    }
    ushort4 u;
    u.x = f2bf(fmaxf(a[0], 0.f)); u.y = f2bf(fmaxf(a[1], 0.f));
    u.z = f2bf(fmaxf(a[2], 0.f)); u.w = f2bf(fmaxf(a[3], 0.f));
    *(ushort4*)&sX[swz(n, cc)] = u;
  }
  __syncthreads();

  if (tid < NPG){
    int c = 1;
    const int4* p4 = (const int4*)sEd;
    #pragma unroll 4
    for (int i = 0; i < NE / 4; ++i){
      int4 v = p4[i];
      c += (v.x == tid) + (v.y == tid) + (v.z == tid) + (v.w == tid);
    }
    sOff[tid] = c;
  }
  __syncthreads();
  {
    int deg = (tid < NPG) ? sOff[tid] : 0;
    int v = deg;
    #pragma unroll
    for (int st = 1; st < 256; st <<= 1){
      if (tid < 256) sSrc[tid] = v;
      __syncthreads();
      if (tid < 256 && tid >= st) v += sSrc[tid - st];
      __syncthreads();
    }
    if (tid < NPG) sOff[tid] = v - deg;
    if (tid == NPG - 1) sOff[NPG] = v;
  }
  __syncthreads();
  if (tid < NPG){
    int p = sOff[tid];
    sSrc[p++] = tid;
    const int4* pd4 = (const int4*)sEd;
    const int4* ps4 = (const int4*)sEs;
    for (int i = 0; i < NE / 4; ++i){
      int4 d = pd4[i]; int4 s = ps4[i];
      if (d.x == tid) sSrc[p++] = s.x;
      if (d.y == tid) sSrc[p++] = s.y;
      if (d.z == tid) sSrc[p++] = s.z;
      if (d.w == tid) sSrc[p++] = s.w;
    }
  }
  __syncthreads();

  {
    f32x4 acc[4][2];
    #pragma unroll
    for (int s = 0; s < 4; ++s){ acc[s][0] = (f32x4){0,0,0,0}; acc[s][1] = (f32x4){0,0,0,0}; }
    #pragma unroll
    for (int kk = 0; kk < 4; ++kk){
      int k0 = kk * 32 + (lg << 2);
      #pragma unroll
      for (int s = 0; s < 4; ++s) if (tact[s]){
        const u16* B0 = W1t + (size_t)(tcb[s] + l15) * 128 + k0;
        const u16* B1 = W1t + (size_t)(tcb[s] + 16 + l15) * 128 + k0;
        short8 bf0 = pack8(*(const ushort4*)B0, *(const ushort4*)(B0 + 16));
        short8 bf1 = pack8(*(const ushort4*)B1, *(const ushort4*)(B1 + 16));
        int rr = tmi[s] * 16 + l15; rr = rr < NPG ? rr : NPG - 1;
        short8 af = pack8(*(const ushort4*)&sX[swz(rr, k0)],
                          *(const ushort4*)&sX[swz(rr, k0 + 16)]);
        acc[s][0] = __builtin_amdgcn_mfma_f32_16x16x32_bf16(af, bf0, acc[s][0], 0, 0, 0);
        acc[s][1] = __builtin_amdgcn_mfma_f32_16x16x32_bf16(af, bf1, acc[s][1], 0, 0, 0);
      }
    }
    #pragma unroll
    for (int s = 0; s < 4; ++s) if (tact[s]){
      int r0 = tmi[s] * 16 + (lg << 2);
      #pragma unroll
      for (int ct = 0; ct < 2; ++ct){
        int col = tcb[s] + ct * 16 + l15;
        #pragma unroll
        for (int r = 0; r < 4; ++r){
          int row = r0 + r;
          if (row < NPG) sY[swz(row, col)] = f2bf(acc[s][ct][r]);
        }
      }
    }
  }
  __syncthreads();

  if (tid < NPG * 4){
    int n = tid >> 2, h = tid & 3;
    float s = 0.f, d = 0.f;
    #pragma unroll
    for (int j = 0; j < 8; ++j){
      int c = h * 32 + j * 4;
      ushort4 xv = *(const ushort4*)&sY[swz(n, c)];
      #pragma unroll
      for (int t = 0; t < 4; ++t){
        float xf = bf2f(((const u16*)&xv)[t]);
        s += xf * sDen[c + t];
        d += xf * sDen[128 + c + t];
      }
    }
    sLs[tid] = s; sLd[tid] = d;
  }
  __syncthreads();

  if (tid < NPG * 4){
    int dst = tid >> 2, h = tid & 3;
    int o0 = sOff[dst], o1 = sOff[dst + 1];
    float ad = sLd[tid];
    float m = -3e38f;
    for (int e = o0; e < o1; ++e) m = fmaxf(m, lrelu(sLs[sSrc[e] * 4 + h] + ad));
    float dn = 0.f;
    for (int e = o0; e < o1; ++e){
      float ee = __expf(lrelu(sLs[sSrc[e] * 4 + h] + ad) - m);
      sW[h * 632 + e] = ee; dn += ee;
    }
    sDen[h * 211 + dst] = 1.0f / (dn + 1e-16f);
  }
  __syncthreads();

  {
    const float b1v0 = b1[cp], b1v1 = b1[cp + 1];
    const float* wp  = sW + hh * 632;
    const float* dnp = sDen + hh * 211;
    for (int dst = wv; dst < NPG; dst += 16){
      int o0 = sOff[dst], o1 = sOff[dst + 1];
      float a0 = 0.f, a1 = 0.f;
      for (int e = o0; e < o1; ++e){
        int sn = sSrc[e];
        u32 f = *(const u32*)&sY[(sn<<7) + (cHi ^ ((sn&15)<<2)) + cLo];
        float w = wp[e];
        a0 += w * lo_bf(f); a1 += w * hi_bf(f);
      }
      float r = dnp[dst];
      *(u32*)&sX[(dst<<7) + (cHi ^ ((dst&15)<<2)) + cLo] =
        pack_bf(fmaxf(a0 * r + b1v0, 0.f), fmaxf(a1 * r + b1v1, 0.f));
    }
  }
  __syncthreads();

  sW[tid] = (tid < 512) ? wms[tid] : wmd[tid - 512];
  __syncthreads();

  if (tid < NPG * 4){
    int n = tid >> 2, h = tid & 3;
    const float* wsp = sW + h * 128;
    const float* wdp = sW + 512 + h * 128;
    float s = 0.f, d = 0.f;
    #pragma unroll
    for (int j = 0; j < 32; ++j){
      ushort4 xv = *(const ushort4*)&sX[swz(n, j * 4)];
      #pragma unroll
      for (int t = 0; t < 4; ++t){
        float xf = bf2f(((const u16*)&xv)[t]);
        s += xf * wsp[j * 4 + t];
        d += xf * wdp[j * 4 + t];
      }
    }
    sLs[tid] = s; sLd[tid] = d;
  }
  __syncthreads();

  if (tid < NPG * 4){
    int dst = tid >> 2, h = tid & 3;
    int o0 = sOff[dst], o1 = sOff[dst + 1];
    float ad = sLd[tid];
    float m = -3e38f;
    for (int e = o0; e < o1; ++e) m = fmaxf(m, lrelu(sLs[sSrc[e] * 4 + h] + ad));
    float dn = 0.f;
    for (int e = o0; e < o1; ++e){
      float ee = __expf(lrelu(sLs[sSrc[e] * 4 + h] + ad) - m);
      sW[h * 632 + e] = ee; dn += ee;
    }
    sDen[h * 211 + dst] = 1.0f / (dn + 1e-16f);
  }
  __syncthreads();

  f32x4 accO[4][2];
  #pragma unroll
  for (int s = 0; s < 4; ++s){ accO[s][0] = (f32x4){0,0,0,0}; accO[s][1] = (f32x4){0,0,0,0}; }
  #pragma unroll 1
  for (int h = 0; h < 4; ++h){
    const float* wp = sW + h * 632;
    for (int dst = wv; dst < NPG; dst += 16){
      int o0 = sOff[dst], o1 = sOff[dst + 1];
      float a0 = 0.f, a1 = 0.f;
      for (int e = o0; e < o1; ++e){
        int sn = sSrc[e];
        u32 f = *(const u32*)&sX[(sn<<7) + (cHi ^ ((sn&15)<<2)) + cLo];
        float w = wp[e];
        a0 += w * lo_bf(f); a1 += w * hi_bf(f);
      }
      float sc = 0.25f * sDen[h * 211 + dst];
      *(u32*)&sY[(dst<<7) + (cHi ^ ((dst&15)<<2)) + cLo] = pack_bf(a0 * sc, a1 * sc);
    }
    __syncthreads();
    #pragma unroll
    for (int kk = 0; kk < 4; ++kk){
      int k0 = kk * 32 + (lg << 2);
      #pragma unroll
      for (int s = 0; s < 4; ++s) if (tact[s]){
        const u16* B0 = W2t + (size_t)(tcb[s] + l15) * 512 + h * 128 + k0;
        const u16* B1 = W2t + (size_t)(tcb[s] + 16 + l15) * 512 + h * 128 + k0;
        short8 bf0 = pack8(*(const ushort4*)B0, *(const ushort4*)(B0 + 16));
        short8 bf1 = pack8(*(const ushort4*)B1, *(const ushort4*)(B1 + 16));
        int rr = tmi[s] * 16 + l15; rr = rr < NPG ? rr : NPG - 1;
        short8 af = pack8(*(const ushort4*)&sY[swz(rr, k0)],
                          *(const ushort4*)&sY[swz(rr, k0 + 16)]);
        accO[s][0] = __builtin_amdgcn_mfma_f32_16x16x32_bf16(af, bf0, accO[s][0], 0, 0, 0);
        accO[s][1] = __builtin_amdgcn_mfma_f32_16x16x32_bf16(af, bf1, accO[s][1], 0, 0, 0);
      }
    }
    __syncthreads();
  }

  #pragma unroll
  for (int s = 0; s < 4; ++s) if (tact[s]){
    int r0 = tmi[s] * 16 + (lg << 2);
    #pragma unroll
    for (int ct = 0; ct < 2; ++ct){
      int col = tcb[s] + ct * 16 + l15;
      float bv = b2[col];
      #pragma unroll
      for (int r = 0; r < 4; ++r){
        int row = r0 + r;
        if (row < NPG) sX[swz(row, col)] = f2bf(fmaxf(accO[s][ct][r] + bv, 0.f));
      }
    }
  }
  __syncthreads();

  if (tid < 812){
    int o = tid >> 2, q = tid & 3;
    float s = 0.f;
    if (o < 200){
      int row = 11 + o;
      #pragma unroll
      for (int j = 0; j < 8; ++j){
        int c = q * 32 + j * 4;
        ushort4 xv = *(const ushort4*)&sX[swz(row, c)];
        s += bf2f(xv.x)*Woff[c] + bf2f(xv.y)*Woff[c+1] + bf2f(xv.z)*Woff[c+2] + bf2f(xv.w)*Woff[c+3];
      }
    } else if (o < 202){
      int j2 = o - 200;
      #pragma unroll
      for (int j = 0; j < 8; ++j){
        int c = q * 32 + j * 4;
        ushort4 xv = *(const ushort4*)&sX[swz(0, c)];
        s += bf2f(xv.x)*Wacc[c*2+j2] + bf2f(xv.y)*Wacc[(c+1)*2+j2]
           + bf2f(xv.z)*Wacc[(c+2)*2+j2] + bf2f(xv.w)*Wacc[(c+3)*2+j2];
      }
    } else {
      #pragma unroll
      for (int j = 0; j < 8; ++j){
        int c = q * 32 + j * 4;
        ushort4 xv = *(const ushort4*)&sX[swz(0, c)];
        s += bf2f(xv.x)*Wvf[c] + bf2f(xv.y)*Wvf[c+1] + bf2f(xv.z)*Wvf[c+2] + bf2f(xv.w)*Wvf[c+3];
      }
    }
    s += __shfl_xor(s, 1);
    s += __shfl_xor(s, 2);
    if (q == 0){
      if (o < 200){
        out[(size_t)b * 203 + 2 + o] = s + boff[0];
      } else if (o < 202){
        int j2 = o - 200;
        float lm = logf(amask[b * 2 + j2]);
        out[(size_t)b * 203 + j2] = s + bacc[j2] + fmaxf(lm, -3.402823466e38f);
      } else {
        out[(size_t)b * 203 + 202] = s + bvf[0];
      }
    }
  }
}

extern "C" void kernel_launch(void* const* d_in, const int* in_sizes, int n_in,
                              void* d_out, int out_size, void* d_ws, size_t ws_size,
                              hipStream_t stream){
  (void)in_sizes; (void)n_in; (void)out_size;
  const float* head = (const float*)d_in[0];
  const float* obj  = (const float*)d_in[1];
  const float* val  = (const float*)d_in[2];
  const int*   eidx = (const int*)d_in[3];
  const float* amask= (const float*)d_in[4];
  const float* Wh   = (const float*)d_in[5];
  const float* bh   = (const float*)d_in[6];
  const float* Wo   = (const float*)d_in[7];
  const float* bo   = (const float*)d_in[8];
  const float* Wv   = (const float*)d_in[9];
  const float* bv   = (const float*)d_in[10];
  const float* W1   = (const float*)d_in[11];
  const float* as1  = (const float*)d_in[12];
  const float* ad1  = (const float*)d_in[13];
  const float* b1   = (const float*)d_in[14];
  const float* W2   = (const float*)d_in[15];
  const float* as2  = (const float*)d_in[16];
  const float* ad2  = (const float*)d_in[17];
  const float* b2   = (const float*)d_in[18];
  const float* Wacc = (const float*)d_in[19];
  const float* bacc = (const float*)d_in[20];
  const float* Woff = (const float*)d_in[21];
  const float* boff = (const float*)d_in[22];
  const float* Wvf  = (const float*)d_in[23];
  const float* bvf  = (const float*)d_in[24];
  float* out = (float*)d_out;

  char* ws = (char*)d_ws;
  u16*   W1t = (u16*)ws;                     // @0,        32768
  u16*   W2t = (u16*)(ws + 32768);           // @32768,   131072
  float* wms = (float*)(ws + 163840);        // @163840,    2048
  float* wmd = (float*)(ws + 165888);        // @165888,    2048

  k_prept<<<320, 256, 0, stream>>>(W1, W2, W1t, W2t);
  k_prepwm<<<4, 256, 0, stream>>>(W2, as2, ad2, wms, wmd);

  const size_t NEED = 178196480;             // split-pipeline ws footprint (fixed: wn = 512*2528*4)
  if (ws_size >= NEED){
    int*   coff = (int*)(ws + 167936);       //   434176 -> ends   602112
    int*   csrc = (int*)(ws + 602112);       //  1294336 -> ends  1896448
    float* aLs  = (float*)(ws + 1896448);    //  1728512 -> ends  3624960
    float* aLd  = (float*)(ws + 3624960);    //  1728512 -> ends  5353472
    float* wn   = (float*)(ws + 5353472);    //  5177344 -> ends 10530816
    float* rden = (float*)(ws + 10530816);   //  1728512 -> ends 12259328
    u16*   x    = (u16*)(ws + 12259328);     // 27656192 -> ends 39915520  (x, then x1)
    u16*   xs1  = (u16*)(ws + 39915520);     // 27656192 -> ends 67571712  (xs1, then out2)
    u16*   y    = (u16*)(ws + 67571712);     // 110624768 -> ends 178196480

    k_embed2<<<NN * 32 / 256, 256, 0, stream>>>(head, obj, val, Wh, bh, Wo, bo, Wv, bv, x);
    k_csr2<<<NB, 256, 0, stream>>>(eidx, coff, csrc);
    k_mm<1, false><<<NN / 128, 256, 0, stream>>>(x, 0, W1t, 128, nullptr, xs1);
    k_att1k<<<NN * 4 / 256, 256, 0, stream>>>(xs1, as1, ad1, aLs, aLd);
    k_smk<<<NB * 4, 256, 0, stream>>>(aLs, aLd, coff, csrc, wn, rden, 1.0f);
    k_gat1k<<<NB * 53, 256, 0, stream>>>(xs1, wn, rden, coff, csrc, b1, x);   // x := x1
    k_att2k<<<NN * 4 / 256, 256, 0, stream>>>(x, wms, wmd, aLs, aLd);
    k_smk<<<NB * 4, 256, 0, stream>>>(aLs, aLd, coff, csrc, wn, rden, 0.25f);
    k_gat2k<<<NB * 53, 256, 0, stream>>>(x, wn, rden, coff, csrc, y);
    k_mm<4, true><<<NN / 128, 256, 0, stream>>>(y, (size_t)NN * 128, W2t, 512, b2, xs1); // xs1 := out2
    k_final2<<<NB * 4, 256, 0, stream>>>(xs1, amask, Wacc, bacc, Woff, boff, Wvf, bvf, out);
  } else {
    k_graph<<<NB, 1024, 0, stream>>>(head, obj, val, eidx, amask,
                                     Wh, bh, Wo, bo, Wv, bv,
                                     W1t, as1, ad1, b1,
                                     W2t, wms, wmd, b2,
                                     Wacc, bacc, Woff, boff, Wvf, bvf, out);
  }
}

// Round 9
// 272.552 us; speedup vs baseline: 1.4272x; 1.4272x over previous
//
#include <hip/hip_runtime.h>

typedef unsigned short u16;
typedef unsigned int u32;
typedef short short8 __attribute__((ext_vector_type(8)));
typedef float f32x4 __attribute__((ext_vector_type(4)));

#define NB   512
#define NPG  211
#define NOBJ 10
#define NVAL 200
#define NE   420
#define NN   (NB * NPG)

__device__ __forceinline__ float bf2f(u16 u){
  union { unsigned i; float f; } v; v.i = ((unsigned)u) << 16; return v.f;
}
__device__ __forceinline__ u16 f2bf(float f){
  union { float f; unsigned i; } v; v.f = f;
  return (u16)((v.i + 0x7FFFu + ((v.i >> 16) & 1u)) >> 16);
}
__device__ __forceinline__ float lo_bf(u32 u){ union{u32 i;float f;}v; v.i=u<<16; return v.f; }
__device__ __forceinline__ float hi_bf(u32 u){ union{u32 i;float f;}v; v.i=u&0xffff0000u; return v.f; }
__device__ __forceinline__ u32 pack_bf(float a, float b){ return (u32)f2bf(a) | ((u32)f2bf(b)<<16); }
__device__ __forceinline__ float lrelu(float s){ return s > 0.f ? s : 0.2f * s; }
__device__ __forceinline__ short8 pack8(ushort4 a, ushort4 b){
  short8 v;
  v[0]=(short)a.x; v[1]=(short)a.y; v[2]=(short)a.z; v[3]=(short)a.w;
  v[4]=(short)b.x; v[5]=(short)b.y; v[6]=(short)b.z; v[7]=(short)b.w;
  return v;
}
// XOR swizzle inside a [*][128] u16 LDS tile, 4-element chunk granularity (legacy kernels).
__device__ __forceinline__ int swz(int r, int c){
  return (r << 7) + (((c & ~3) ^ ((r & 15) << 2)) | (c & 3));
}
// 16B-chunk swizzled element index for the new k_mm LDS tiles.
__device__ __forceinline__ int s16(int r, int c){
  return (r << 7) + ((((c >> 3) ^ (r & 15)) << 3) | (c & 7));
}

#define AS_GLOBAL(p) ((const __attribute__((address_space(1))) void*)((const void*)(p)))
#define AS_LDS(p)    ((__attribute__((address_space(3))) void*)((void*)(p)))

// ---------------- prep: transposed weights, f32 -> bf16 (ws) ----------------
__global__ __launch_bounds__(256) void k_prept(const float* __restrict__ W1, const float* __restrict__ W2,
                                               u16* __restrict__ W1t, u16* __restrict__ W2t){
  int gid = blockIdx.x * 256 + threadIdx.x;      // 320 blocks -> 81920
  if (gid < 16384){
    int k = gid >> 7, n = gid & 127;
    W1t[n * 128 + k] = f2bf(W1[k * 128 + n]);
  } else {
    int t = gid - 16384;
    int n = t >> 9, kk = t & 511;
    int h = kk >> 7, c = kk & 127;
    W2t[n * 512 + kk] = f2bf(W2[c * 512 + h * 128 + n]);
  }
}

// ---------------- prep: layer-2 attention vectors (ws, f32) ----------------
__global__ __launch_bounds__(256) void k_prepwm(const float* __restrict__ W2, const float* __restrict__ as2,
                                                const float* __restrict__ ad2,
                                                float* __restrict__ wms, float* __restrict__ wmd){
  int gid = blockIdx.x * 256 + threadIdx.x;      // 4 blocks -> 1024
  int which = gid >> 9, hk = gid & 511;
  int h = hk >> 7, k = hk & 127;
  const float* av = which ? ad2 : as2;
  float s = 0.f;
  for (int j = 0; j < 128; ++j)
    s += W2[k * 512 + h * 128 + j] * av[h * 128 + j];
  (which ? wmd : wms)[hk] = s;
}

// =====================================================================
// ===================== SPLIT PIPELINE KERNELS ========================
// =====================================================================

// ---- embed: x[n][c] bf16 (linear layout) ----
__global__ __launch_bounds__(256) void k_embed2(
    const float* __restrict__ head, const float* __restrict__ obj, const float* __restrict__ val,
    const float* __restrict__ Wh, const float* __restrict__ bh,
    const float* __restrict__ Wo, const float* __restrict__ bo,
    const float* __restrict__ Wv, const float* __restrict__ bv,
    u16* __restrict__ x){
  int gid = blockIdx.x * 256 + threadIdx.x;      // 13504 blocks = NN*32
  int n = gid >> 5, cc = (gid & 31) << 2;
  int g = n / NPG, loc = n - g * NPG;
  float a[4];
  if (loc == 0){
    const float* in = head + (size_t)g * 2;
    float i0 = in[0], i1 = in[1];
    #pragma unroll
    for (int t = 0; t < 4; ++t){ int c = cc + t; a[t] = bh[c] + i0 * Wh[c] + i1 * Wh[128 + c]; }
  } else if (loc <= NOBJ){
    const float* in = obj + ((size_t)g * NOBJ + (loc - 1)) * 2;
    float i0 = in[0], i1 = in[1];
    #pragma unroll
    for (int t = 0; t < 4; ++t){ int c = cc + t; a[t] = bo[c] + i0 * Wo[c] + i1 * Wo[128 + c]; }
  } else {
    const float* in = val + ((size_t)g * NVAL + (loc - 11)) * 5;
    float f[5];
    #pragma unroll
    for (int k = 0; k < 5; ++k) f[k] = in[k];
    #pragma unroll
    for (int t = 0; t < 4; ++t){
      int c = cc + t; float s = bv[c];
      #pragma unroll
      for (int k = 0; k < 5; ++k) s += f[k] * Wv[k * 128 + c];
      a[t] = s;
    }
  }
  ushort4 u;
  u.x = f2bf(fmaxf(a[0], 0.f)); u.y = f2bf(fmaxf(a[1], 0.f));
  u.z = f2bf(fmaxf(a[2], 0.f)); u.w = f2bf(fmaxf(a[3], 0.f));
  *(ushort4*)&x[(size_t)n * 128 + cc] = u;
}

// ---- CSR build: per-graph block ----
__global__ __launch_bounds__(256) void k_csr2(const int* __restrict__ eidx,
                                              int* __restrict__ coff, int* __restrict__ csrc){
  __shared__ int sEs[420], sEd[420], sTmp[256], sOff[212], sSrc[632];
  int g = blockIdx.x, tid = threadIdx.x;
  const int4* e4 = (const int4*)(eidx + (size_t)g * 840);
  for (int i = tid; i < 105; i += 256){ ((int4*)sEs)[i] = e4[i]; ((int4*)sEd)[i] = e4[105 + i]; }
  __syncthreads();
  int deg = 0;
  if (tid < NPG){
    deg = 1;
    const int4* p4 = (const int4*)sEd;
    #pragma unroll 4
    for (int i = 0; i < 105; ++i){
      int4 v = p4[i];
      deg += (v.x == tid) + (v.y == tid) + (v.z == tid) + (v.w == tid);
    }
  }
  int v = deg;
  #pragma unroll
  for (int st = 1; st < 256; st <<= 1){
    sTmp[tid] = v;
    __syncthreads();
    if (tid >= st) v += sTmp[tid - st];
    __syncthreads();
  }
  if (tid < NPG) sOff[tid] = v - deg;
  if (tid == NPG - 1) sOff[NPG] = v;
  __syncthreads();
  if (tid < NPG){
    int p = sOff[tid];
    sSrc[p++] = tid;                              // self loop first
    const int4* pd4 = (const int4*)sEd;
    const int4* ps4 = (const int4*)sEs;
    for (int i = 0; i < 105; ++i){
      int4 d = pd4[i]; int4 s = ps4[i];
      if (d.x == tid) sSrc[p++] = s.x;
      if (d.y == tid) sSrc[p++] = s.y;
      if (d.z == tid) sSrc[p++] = s.z;
      if (d.w == tid) sSrc[p++] = s.w;
    }
  }
  __syncthreads();
  if (tid < 212) coff[(size_t)g * 212 + tid] = sOff[tid];
  for (int i = tid; i < 631; i += 256) csrc[(size_t)g * 632 + i] = sSrc[i];
}

// ---- MFMA GEMM (rebuilt): C[Mx128] = sum_ch A_ch[Mx128] @ Bt[128 x ...]^T ----
// 844 blocks x 512 thr (8 waves). Wave w owns rows [w*16, w*16+16) x all 128 cols.
// A and B chunk tiles staged to LDS via global_load_lds (16B), s16 source-swizzle.
template<int KCH, bool RELU>
__global__ __launch_bounds__(512) void k_mm(const u16* __restrict__ A, size_t chunkStride,
                                            const u16* __restrict__ Bt, int bstride,
                                            const float* __restrict__ bias, u16* __restrict__ C){
  __shared__ u16 sA[128 * 128];
  __shared__ u16 sB[128 * 128];
  const int tid = threadIdx.x, lane = tid & 63, w = tid >> 6;
  const int l15 = lane & 15, lg = lane >> 4;
  const int row0 = blockIdx.x * 128;
  f32x4 acc[8];
  #pragma unroll
  for (int ni = 0; ni < 8; ++ni) acc[ni] = (f32x4){0,0,0,0};

  #pragma unroll 1
  for (int ch = 0; ch < KCH; ++ch){
    const u16* Ab = A + (size_t)ch * chunkStride + (size_t)row0 * 128;
    const u16* Bb = Bt + ch * 128;
    // stage: wave w covers rows [w*16, w*16+16) of both tiles; 4 issues each.
    #pragma unroll
    for (int i = 0; i < 4; ++i){
      int r = w * 16 + i * 4 + (lane >> 4);          // per-lane row (4 rows / issue)
      int c16 = lane & 15;
      int sw = (c16 ^ (r & 15)) << 4;                // swizzled 16B-chunk byte offset
      __builtin_amdgcn_global_load_lds(AS_GLOBAL((const char*)(Ab + (size_t)r * 128) + sw),
                                       AS_LDS(&sA[(w * 16 + i * 4) * 128]), 16, 0, 0);
      __builtin_amdgcn_global_load_lds(AS_GLOBAL((const char*)(Bb + (size_t)r * bstride) + sw),
                                       AS_LDS(&sB[(w * 16 + i * 4) * 128]), 16, 0, 0);
    }
    __syncthreads();                                  // drains vmcnt -> LDS ready
    #pragma unroll
    for (int kk = 0; kk < 4; ++kk){
      int k0 = kk * 32 + lg * 4;
      int rr = w * 16 + l15;
      short8 af = pack8(*(const ushort4*)&sA[s16(rr, k0)],
                        *(const ushort4*)&sA[s16(rr, k0 + 16)]);
      #pragma unroll
      for (int ni = 0; ni < 8; ++ni){
        int cc = ni * 16 + l15;
        short8 bf = pack8(*(const ushort4*)&sB[s16(cc, k0)],
                          *(const ushort4*)&sB[s16(cc, k0 + 16)]);
        acc[ni] = __builtin_amdgcn_mfma_f32_16x16x32_bf16(af, bf, acc[ni], 0, 0, 0);
      }
    }
    __syncthreads();                                  // protect LDS before next chunk
  }
  const int r0 = row0 + w * 16 + lg * 4;
  #pragma unroll
  for (int ni = 0; ni < 8; ++ni){
    int col = ni * 16 + l15;
    float bv = RELU ? bias[col] : 0.f;
    #pragma unroll
    for (int r = 0; r < 4; ++r){
      float v = acc[ni][r];
      if (RELU) v = fmaxf(v + bv, 0.f);
      C[(size_t)(r0 + r) * 128 + col] = f2bf(v);
    }
  }
}

// ---- att1 logits: thread per (n,h), 32-col head slice ----
__global__ __launch_bounds__(256) void k_att1k(const u16* __restrict__ xs1,
                                               const float* __restrict__ as1, const float* __restrict__ ad1,
                                               float* __restrict__ Ls, float* __restrict__ Ld){
  int t = blockIdx.x * 256 + threadIdx.x;        // 1688 blocks = NN*4
  int n = t >> 2, h = t & 3;
  const u16* xr = xs1 + (size_t)n * 128 + h * 32;
  float s = 0.f, d = 0.f;
  #pragma unroll
  for (int j = 0; j < 8; ++j){
    ushort4 xv = *(const ushort4*)(xr + j * 4);
    #pragma unroll
    for (int q = 0; q < 4; ++q){
      float xf = bf2f(((const u16*)&xv)[q]);
      int c = h * 32 + j * 4 + q;
      s += xf * as1[c];
      d += xf * ad1[c];
    }
  }
  Ls[t] = s; Ld[t] = d;
}

// ---- att2 logits: thread per (n,h), full 128-col dot with wms/wmd ----
__global__ __launch_bounds__(256) void k_att2k(const u16* __restrict__ x1,
                                               const float* __restrict__ wms, const float* __restrict__ wmd,
                                               float* __restrict__ Ls, float* __restrict__ Ld){
  __shared__ float sw[1024];
  int tid = threadIdx.x;
  for (int i = tid; i < 512; i += 256) sw[i] = wms[i];
  for (int i = tid; i < 512; i += 256) sw[512 + i] = wmd[i];
  __syncthreads();
  int t = blockIdx.x * 256 + tid;                // 1688 blocks
  int n = t >> 2, h = t & 3;
  const u16* xr = x1 + (size_t)n * 128;
  const float* wsp = sw + h * 128;
  const float* wdp = sw + 512 + h * 128;
  float s = 0.f, d = 0.f;
  #pragma unroll
  for (int j = 0; j < 32; ++j){
    ushort4 xv = *(const ushort4*)(xr + j * 4);
    #pragma unroll
    for (int q = 0; q < 4; ++q){
      float xf = bf2f(((const u16*)&xv)[q]);
      s += xf * wsp[j * 4 + q];
      d += xf * wdp[j * 4 + q];
    }
  }
  Ls[t] = s; Ld[t] = d;
}

// ---- softmax weights: thread per (dst,h); writes raw exp + folded recip-denom ----
__global__ __launch_bounds__(256) void k_smk(const float* __restrict__ Ls, const float* __restrict__ Ld,
                                             const int* __restrict__ coff, const int* __restrict__ csrc,
                                             float* __restrict__ wn, float* __restrict__ rden, float fold){
  int g = blockIdx.x >> 2;
  int t = ((blockIdx.x & 3) << 8) + threadIdx.x; // 0..1023
  if (t >= NPG * 4) return;
  int dst = t >> 2, h = t & 3;
  int gb = g * NPG;
  int o0 = coff[(size_t)g * 212 + dst], o1 = coff[(size_t)g * 212 + dst + 1];
  const int* sp = csrc + (size_t)g * 632;
  float ad = Ld[(size_t)(gb + dst) * 4 + h];
  float m = -3e38f;
  for (int e = o0; e < o1; ++e) m = fmaxf(m, lrelu(Ls[(size_t)(gb + sp[e]) * 4 + h] + ad));
  float dn = 0.f;
  float* wp = wn + (size_t)g * 2528 + h * 632;
  for (int e = o0; e < o1; ++e){
    float ee = __expf(lrelu(Ls[(size_t)(gb + sp[e]) * 4 + h] + ad) - m);
    wp[e] = ee; dn += ee;
  }
  rden[(size_t)(gb + dst) * 4 + h] = fold / (dn + 1e-16f);
}

// ---- gat1: wave per dst, thread per col-pair; x1 = relu(b1 + A~xs1) ----
__global__ __launch_bounds__(256) void k_gat1k(const u16* __restrict__ xs1,
                                               const float* __restrict__ wn, const float* __restrict__ rden,
                                               const int* __restrict__ coff, const int* __restrict__ csrc,
                                               const float* __restrict__ b1, u16* __restrict__ x1){
  int bid = blockIdx.x;                          // 512*53
  int g = bid / 53, ch = bid - g * 53;
  int dst = ch * 4 + (threadIdx.x >> 6);
  if (dst >= NPG) return;
  int lane = threadIdx.x & 63;
  int cp = lane << 1, hh = lane >> 4;
  int gb = g * NPG;
  int o0 = coff[(size_t)g * 212 + dst], o1 = coff[(size_t)g * 212 + dst + 1];
  const int* sp = csrc + (size_t)g * 632;
  const float* wp = wn + (size_t)g * 2528 + hh * 632;
  float a0 = 0.f, a1 = 0.f;
  for (int e = o0; e < o1; ++e){
    int src = sp[e];
    u32 f = *(const u32*)&xs1[(size_t)(gb + src) * 128 + cp];
    float w = wp[e];
    a0 += w * lo_bf(f); a1 += w * hi_bf(f);
  }
  float rv = rden[(size_t)(gb + dst) * 4 + hh];
  *(u32*)&x1[(size_t)(gb + dst) * 128 + cp] =
    pack_bf(fmaxf(a0 * rv + b1[cp], 0.f), fmaxf(a1 * rv + b1[cp + 1], 0.f));
}

// ---- gat2: wave per dst, all 4 heads per thread; writes y[h][n][c] (fold=0.25 in rden) ----
__global__ __launch_bounds__(256) void k_gat2k(const u16* __restrict__ x1,
                                               const float* __restrict__ wn, const float* __restrict__ rden,
                                               const int* __restrict__ coff, const int* __restrict__ csrc,
                                               u16* __restrict__ y){
  int bid = blockIdx.x;                          // 512*53
  int g = bid / 53, ch = bid - g * 53;
  int dst = ch * 4 + (threadIdx.x >> 6);
  if (dst >= NPG) return;
  int lane = threadIdx.x & 63;
  int cp = lane << 1;
  int gb = g * NPG;
  int o0 = coff[(size_t)g * 212 + dst], o1 = coff[(size_t)g * 212 + dst + 1];
  const int* sp = csrc + (size_t)g * 632;
  const float* wb = wn + (size_t)g * 2528;
  float a0[4] = {0,0,0,0}, a1[4] = {0,0,0,0};
  for (int e = o0; e < o1; ++e){
    int src = sp[e];
    u32 f = *(const u32*)&x1[(size_t)(gb + src) * 128 + cp];
    float xl = lo_bf(f), xh = hi_bf(f);
    #pragma unroll
    for (int h = 0; h < 4; ++h){
      float w = wb[h * 632 + e];
      a0[h] += w * xl; a1[h] += w * xh;
    }
  }
  #pragma unroll
  for (int h = 0; h < 4; ++h){
    float rv = rden[(size_t)(gb + dst) * 4 + h];
    *(u32*)&y[(size_t)h * NN * 128 + (size_t)(gb + dst) * 128 + cp] =
      pack_bf(a0[h] * rv, a1[h] * rv);
  }
}

// ---- final projections: 4 blocks/graph, 4 threads/output ----
__global__ __launch_bounds__(256) void k_final2(const u16* __restrict__ out2, const float* __restrict__ amask,
                                                const float* __restrict__ Wacc, const float* __restrict__ bacc,
                                                const float* __restrict__ Woff, const float* __restrict__ boff,
                                                const float* __restrict__ Wvf,  const float* __restrict__ bvf,
                                                float* __restrict__ out){
  int g = blockIdx.x >> 2;
  int t = ((blockIdx.x & 3) << 8) + threadIdx.x; // 0..1023
  if (t >= 812) return;
  int o = t >> 2, q = t & 3;
  float s = 0.f;
  if (o < 200){
    const u16* row = out2 + (size_t)(g * NPG + 11 + o) * 128;
    #pragma unroll
    for (int j = 0; j < 8; ++j){
      int c = q * 32 + j * 4;
      ushort4 xv = *(const ushort4*)(row + c);
      s += bf2f(xv.x)*Woff[c] + bf2f(xv.y)*Woff[c+1] + bf2f(xv.z)*Woff[c+2] + bf2f(xv.w)*Woff[c+3];
    }
  } else if (o < 202){
    int j2 = o - 200;
    const u16* row = out2 + (size_t)(g * NPG) * 128;
    #pragma unroll
    for (int j = 0; j < 8; ++j){
      int c = q * 32 + j * 4;
      ushort4 xv = *(const ushort4*)(row + c);
      s += bf2f(xv.x)*Wacc[c*2+j2] + bf2f(xv.y)*Wacc[(c+1)*2+j2]
         + bf2f(xv.z)*Wacc[(c+2)*2+j2] + bf2f(xv.w)*Wacc[(c+3)*2+j2];
    }
  } else {
    const u16* row = out2 + (size_t)(g * NPG) * 128;
    #pragma unroll
    for (int j = 0; j < 8; ++j){
      int c = q * 32 + j * 4;
      ushort4 xv = *(const ushort4*)(row + c);
      s += bf2f(xv.x)*Wvf[c] + bf2f(xv.y)*Wvf[c+1] + bf2f(xv.z)*Wvf[c+2] + bf2f(xv.w)*Wvf[c+3];
    }
  }
  s += __shfl_xor(s, 1);
  s += __shfl_xor(s, 2);
  if (q == 0){
    if (o < 200){
      out[(size_t)g * 203 + 2 + o] = s + boff[0];
    } else if (o < 202){
      int j2 = o - 200;
      float lm = logf(amask[g * 2 + j2]);
      out[(size_t)g * 203 + j2] = s + bacc[j2] + fmaxf(lm, -3.402823466e38f);
    } else {
      out[(size_t)g * 203 + 202] = s + bvf[0];
    }
  }
}

extern "C" void kernel_launch(void* const* d_in, const int* in_sizes, int n_in,
                              void* d_out, int out_size, void* d_ws, size_t ws_size,
                              hipStream_t stream){
  (void)in_sizes; (void)n_in; (void)out_size; (void)ws_size;
  const float* head = (const float*)d_in[0];
  const float* obj  = (const float*)d_in[1];
  const float* val  = (const float*)d_in[2];
  const int*   eidx = (const int*)d_in[3];
  const float* amask= (const float*)d_in[4];
  const float* Wh   = (const float*)d_in[5];
  const float* bh   = (const float*)d_in[6];
  const float* Wo   = (const float*)d_in[7];
  const float* bo   = (const float*)d_in[8];
  const float* Wv   = (const float*)d_in[9];
  const float* bv   = (const float*)d_in[10];
  const float* W1   = (const float*)d_in[11];
  const float* as1  = (const float*)d_in[12];
  const float* ad1  = (const float*)d_in[13];
  const float* b1   = (const float*)d_in[14];
  const float* W2   = (const float*)d_in[15];
  const float* as2  = (const float*)d_in[16];
  const float* ad2  = (const float*)d_in[17];
  const float* b2   = (const float*)d_in[18];
  const float* Wacc = (const float*)d_in[19];
  const float* bacc = (const float*)d_in[20];
  const float* Woff = (const float*)d_in[21];
  const float* boff = (const float*)d_in[22];
  const float* Wvf  = (const float*)d_in[23];
  const float* bvf  = (const float*)d_in[24];
  float* out = (float*)d_out;

  char* ws = (char*)d_ws;
  u16*   W1t = (u16*)ws;                     // @0,        32768
  u16*   W2t = (u16*)(ws + 32768);           // @32768,   131072
  float* wms = (float*)(ws + 163840);        // @163840,    2048
  float* wmd = (float*)(ws + 165888);        // @165888,    2048

  k_prept<<<320, 256, 0, stream>>>(W1, W2, W1t, W2t);
  k_prepwm<<<4, 256, 0, stream>>>(W2, as2, ad2, wms, wmd);

  int*   coff = (int*)(ws + 167936);       //   434176 -> ends   602112
  int*   csrc = (int*)(ws + 602112);       //  1294336 -> ends  1896448
  float* aLs  = (float*)(ws + 1896448);    //  1728512 -> ends  3624960
  float* aLd  = (float*)(ws + 3624960);    //  1728512 -> ends  5353472
  float* wn   = (float*)(ws + 5353472);    //  5177344 -> ends 10530816
  float* rden = (float*)(ws + 10530816);   //  1728512 -> ends 12259328
  u16*   x    = (u16*)(ws + 12259328);     // 27656192 -> ends 39915520  (x, then x1)
  u16*   xs1  = (u16*)(ws + 39915520);     // 27656192 -> ends 67571712  (xs1, then out2)
  u16*   y    = (u16*)(ws + 67571712);     // 110624768 -> ends 178196480 (ws_size verified >= this in R8)

  k_embed2<<<NN * 32 / 256, 256, 0, stream>>>(head, obj, val, Wh, bh, Wo, bo, Wv, bv, x);
  k_csr2<<<NB, 256, 0, stream>>>(eidx, coff, csrc);
  k_mm<1, false><<<NN / 128, 512, 0, stream>>>(x, 0, W1t, 128, nullptr, xs1);
  k_att1k<<<NN * 4 / 256, 256, 0, stream>>>(xs1, as1, ad1, aLs, aLd);
  k_smk<<<NB * 4, 256, 0, stream>>>(aLs, aLd, coff, csrc, wn, rden, 1.0f);
  k_gat1k<<<NB * 53, 256, 0, stream>>>(xs1, wn, rden, coff, csrc, b1, x);   // x := x1
  k_att2k<<<NN * 4 / 256, 256, 0, stream>>>(x, wms, wmd, aLs, aLd);
  k_smk<<<NB * 4, 256, 0, stream>>>(aLs, aLd, coff, csrc, wn, rden, 0.25f);
  k_gat2k<<<NB * 53, 256, 0, stream>>>(x, wn, rden, coff, csrc, y);
  k_mm<4, true><<<NN / 128, 512, 0, stream>>>(y, (size_t)NN * 128, W2t, 512, b2, xs1); // xs1 := out2
  k_final2<<<NB * 4, 256, 0, stream>>>(xs1, amask, Wacc, bacc, Woff, boff, Wvf, bvf, out);
}